// Round 1
// baseline (3561.972 us; speedup 1.0000x reference)
//
#include <hip/hip_runtime.h>

#define NU 80000
#define NI 40000
#define DD 128
#define NNZ_E 2000000
#define EPSN 1e-12f

struct Batch {
  const int* rows[4];
  const int* cols[4];
  const float* vals[4];
};

// ---------------- CSR build ----------------

__global__ __launch_bounds__(256) void hist_k(Batch ba, int b0, int* cntU, int* cntI, int nnz) {
  int b = blockIdx.y;
  const int* __restrict__ rows = ba.rows[b0 + b];
  const int* __restrict__ cols = ba.cols[b0 + b];
  int* cu = cntU + (size_t)b * NU;
  int* ci = cntI + (size_t)b * NI;
  int stride = blockDim.x * gridDim.x;
  for (int e = blockIdx.x * blockDim.x + threadIdx.x; e < nnz; e += stride) {
    atomicAdd(&cu[rows[e]], 1);
    atomicAdd(&ci[cols[e]], 1);
  }
}

// one block per array; shuffle-based chunked exclusive scan
__global__ __launch_bounds__(1024) void scan_k(int* cntU, int* cntI, int* rpU, int* rpI,
                                               int* curU, int* curI, int batch) {
  __shared__ int wsum[17];
  int a = blockIdx.x;
  int n; int* cnt; int* rp; int* cur;
  if (a < batch) {
    n = NU; cnt = cntU + (size_t)a * NU; rp = rpU + (size_t)a * (NU + 1); cur = curU + (size_t)a * NU;
  } else {
    int j = a - batch;
    n = NI; cnt = cntI + (size_t)j * NI; rp = rpI + (size_t)j * (NI + 1); cur = curI + (size_t)j * NI;
  }
  int t = threadIdx.x;
  int lane = t & 63, w = t >> 6;
  int nw = blockDim.x >> 6;
  int carry = 0;
  for (int base = 0; base < n; base += blockDim.x) {
    int i = base + t;
    int v = (i < n) ? cnt[i] : 0;
    int s = v;
    #pragma unroll
    for (int off = 1; off < 64; off <<= 1) {
      int x = __shfl_up(s, off);
      if (lane >= off) s += x;
    }
    if (lane == 63) wsum[w] = s;
    __syncthreads();
    if (t == 0) {
      int run = 0;
      for (int k = 0; k < nw; k++) { int x = wsum[k]; wsum[k] = run; run += x; }
      wsum[16] = run;
    }
    __syncthreads();
    int excl = carry + wsum[w] + (s - v);
    if (i < n) { rp[i] = excl; cur[i] = excl; }
    carry += wsum[16];
    __syncthreads();
  }
  if (t == 0) rp[n] = carry;
}

__global__ __launch_bounds__(256) void scatter_k(Batch ba, int b0, int* curU, int* curI,
                                                 int2* pairsU, int2* pairsI, int nnz) {
  int b = blockIdx.y;
  const int* __restrict__ rows = ba.rows[b0 + b];
  const int* __restrict__ cols = ba.cols[b0 + b];
  const float* __restrict__ vals = ba.vals[b0 + b];
  int* cu = curU + (size_t)b * NU;
  int* ci = curI + (size_t)b * NI;
  int2* pu = pairsU + (size_t)b * NNZ_E;
  int2* pi = pairsI + (size_t)b * NNZ_E;
  int stride = blockDim.x * gridDim.x;
  for (int e = blockIdx.x * blockDim.x + threadIdx.x; e < nnz; e += stride) {
    int r = rows[e], c = cols[e];
    int v = __float_as_int(vals[e]);
    int su = atomicAdd(&cu[r], 1);
    pu[su] = make_int2(c, v);
    int si = atomicAdd(&ci[c], 1);
    pi[si] = make_int2(r, v);
  }
}

// ---------------- gather SpMM: one 32-lane group per dst row ----------------

__global__ __launch_bounds__(256) void gather_k(const int* __restrict__ rp, const int2* __restrict__ pairs,
                                                const float* __restrict__ x, float* __restrict__ out1,
                                                float* __restrict__ out2, int nrows) {
  int gpb = blockDim.x >> 5;
  int gid = blockIdx.x * gpb + (threadIdx.x >> 5);
  int lane = threadIdx.x & 31;
  int tot = gridDim.x * gpb;
  const float4* __restrict__ x4 = (const float4*)x;
  for (int r = gid; r < nrows; r += tot) {
    int beg = rp[r], end = rp[r + 1];
    float4 a0 = make_float4(0.f, 0.f, 0.f, 0.f);
    float4 a1 = make_float4(0.f, 0.f, 0.f, 0.f);
    int e = beg;
    for (; e + 3 < end; e += 4) {
      int2 p0 = pairs[e], p1 = pairs[e + 1], p2 = pairs[e + 2], p3 = pairs[e + 3];
      float4 x0 = x4[(size_t)p0.x * 32 + lane];
      float4 x1 = x4[(size_t)p1.x * 32 + lane];
      float4 x2 = x4[(size_t)p2.x * 32 + lane];
      float4 x3 = x4[(size_t)p3.x * 32 + lane];
      float v0 = __int_as_float(p0.y), v1 = __int_as_float(p1.y);
      float v2 = __int_as_float(p2.y), v3 = __int_as_float(p3.y);
      a0.x += v0 * x0.x; a0.y += v0 * x0.y; a0.z += v0 * x0.z; a0.w += v0 * x0.w;
      a1.x += v1 * x1.x; a1.y += v1 * x1.y; a1.z += v1 * x1.z; a1.w += v1 * x1.w;
      a0.x += v2 * x2.x; a0.y += v2 * x2.y; a0.z += v2 * x2.z; a0.w += v2 * x2.w;
      a1.x += v3 * x3.x; a1.y += v3 * x3.y; a1.z += v3 * x3.z; a1.w += v3 * x3.w;
    }
    for (; e < end; e++) {
      int2 p = pairs[e];
      float4 xv = x4[(size_t)p.x * 32 + lane];
      float v = __int_as_float(p.y);
      a0.x += v * xv.x; a0.y += v * xv.y; a0.z += v * xv.z; a0.w += v * xv.w;
    }
    float4 res = make_float4(a0.x + a1.x, a0.y + a1.y, a0.z + a1.z, a0.w + a1.w);
    ((float4*)out1)[(size_t)r * 32 + lane] = res;
    if (out2) ((float4*)out2)[(size_t)r * 32 + lane] = res;
  }
}

// ---------------- mean(4 slices) @ W, sigmoid ----------------

__global__ __launch_bounds__(256) void gemm_sig_k(const float* __restrict__ x, size_t sstride,
                                                  const float* __restrict__ W, float* __restrict__ out,
                                                  int n) {
  __shared__ float wl[DD * DD];
  __shared__ float rl[8][DD];
  for (int i = threadIdx.x; i < DD * DD / 4; i += blockDim.x)
    ((float4*)wl)[i] = ((const float4*)W)[i];
  int c = threadIdx.x & 127;
  int g = threadIdx.x >> 7;  // 0..1; handles rows g*4 .. g*4+3
  int row0 = blockIdx.x * 64;
  for (int rr = 0; rr < 64; rr += 8) {
    int rbase = row0 + rr;
    __syncthreads();
    for (int i = threadIdx.x; i < 8 * DD; i += blockDim.x) {
      int lr = i >> 7, lc = i & 127;
      int r = rbase + lr;
      float m = 0.f;
      if (r < n) {
        size_t off = (size_t)r * DD + lc;
        m = 0.25f * (x[off] + x[off + sstride] + x[off + 2 * sstride] + x[off + 3 * sstride]);
      }
      rl[lr][lc] = m;
    }
    __syncthreads();
    float acc0 = 0.f, acc1 = 0.f, acc2 = 0.f, acc3 = 0.f;
    #pragma unroll 4
    for (int k = 0; k < DD; k++) {
      float wv = wl[k * DD + c];
      acc0 += rl[g * 4 + 0][k] * wv;
      acc1 += rl[g * 4 + 1][k] * wv;
      acc2 += rl[g * 4 + 2][k] * wv;
      acc3 += rl[g * 4 + 3][k] * wv;
    }
    float accs[4] = {acc0, acc1, acc2, acc3};
    for (int j = 0; j < 4; j++) {
      int r = rbase + g * 4 + j;
      if (r < n) out[(size_t)r * DD + c] = 1.f / (1.f + __expf(-accs[j]));
    }
  }
}

// ---------------- column (node-axis) sum of squares, then scale ----------------

__global__ __launch_bounds__(256) void colsq_k(const float* __restrict__ base, size_t sstride, int n,
                                               float* __restrict__ sums) {
  int b = blockIdx.y;
  const float* x = base + (size_t)b * sstride;
  int c = threadIdx.x & 127;
  int rh = threadIdx.x >> 7;
  float acc = 0.f;
  for (int r = blockIdx.x * 2 + rh; r < n; r += gridDim.x * 2) {
    float v = x[(size_t)r * DD + c];
    acc += v * v;
  }
  __shared__ float red[256];
  red[threadIdx.x] = acc;
  __syncthreads();
  if (threadIdx.x < 128) atomicAdd(&sums[b * DD + threadIdx.x], red[threadIdx.x] + red[threadIdx.x + 128]);
}

__global__ void inv_k(const float* __restrict__ sums, float* __restrict__ inv, int n) {
  int i = blockIdx.x * blockDim.x + threadIdx.x;
  if (i < n) inv[i] = 1.f / fmaxf(sqrtf(sums[i]), EPSN);
}

__global__ __launch_bounds__(256) void scale_k(float* __restrict__ base, size_t slice_f4,
                                               const float* __restrict__ inv) {
  int b = blockIdx.y;
  float4* b4 = (float4*)base + (size_t)b * slice_f4;
  const float4* inv4 = (const float4*)inv + (size_t)b * 32;
  size_t stride = (size_t)blockDim.x * gridDim.x;
  for (size_t i = (size_t)blockIdx.x * blockDim.x + threadIdx.x; i < slice_f4; i += stride) {
    float4 s = inv4[i & 31];
    float4 v = b4[i];
    v.x *= s.x; v.y *= s.y; v.z *= s.z; v.w *= s.w;
    b4[i] = v;
  }
}

// ---------------- host ----------------

extern "C" void kernel_launch(void* const* d_in, const int* in_sizes, int n_in,
                              void* d_out, int out_size, void* d_ws, size_t ws_size,
                              hipStream_t stream) {
  const float* user_emb = (const float*)d_in[0];
  const float* item_emb = (const float*)d_in[1];
  const float* uu[4] = {(const float*)d_in[2], (const float*)d_in[4], (const float*)d_in[6], user_emb};
  const float* ii[4] = {(const float*)d_in[3], (const float*)d_in[5], (const float*)d_in[7], item_emb};
  const float* u_w = (const float*)d_in[8];
  const float* i_w = (const float*)d_in[9];
  Batch ba;
  for (int b = 0; b < 4; b++) {
    ba.rows[b] = (const int*)d_in[10 + 3 * b];
    ba.cols[b] = (const int*)d_in[11 + 3 * b];
    ba.vals[b] = (const float*)d_in[12 + 3 * b];
  }

  float* out = (float*)d_out;
  float* user_out = out;
  float* item_out = out + (size_t)NU * DD;
  float* l2nU = item_out + (size_t)NI * DD;
  float* l2nI = l2nU + (size_t)4 * NU * DD;
  float* u_slot[3];
  float* i_slot[3];
  {
    float* p = l2nI + (size_t)4 * NI * DD;
    for (int b = 0; b < 3; b++) {
      u_slot[b] = p; p += (size_t)NU * DD;
      i_slot[b] = p; p += (size_t)NI * DD;
    }
  }

  // workspace layout (batch behaviors in flight; fall back if ws is small)
  auto need = [](int batch) {
    size_t s = 0;
    s += (size_t)batch * NNZ_E * 8 * 2;              // pairsU + pairsI
    s += (size_t)batch * (NU + NI) * 4;              // cnt
    s += (size_t)batch * ((NU + 1) + (NI + 1)) * 4;  // row_ptr
    s += (size_t)batch * (NU + NI) * 4;              // cursors
    s += 8 * DD * 4 * 2;                             // colsums + inv
    s += 32 * 256;                                   // alignment slop
    return s;
  };
  int batch = (ws_size >= need(4)) ? 4 : 1;

  char* w = (char*)d_ws;
  auto alloc = [&](size_t bytes) {
    char* r = w;
    w += (bytes + 255) & ~(size_t)255;
    return r;
  };
  int2* pairsU = (int2*)alloc((size_t)batch * NNZ_E * 8);
  int2* pairsI = (int2*)alloc((size_t)batch * NNZ_E * 8);
  int* cntU = (int*)alloc((size_t)batch * NU * 4);
  int* cntI = (int*)alloc((size_t)batch * NI * 4);
  int* rpU = (int*)alloc((size_t)batch * (NU + 1) * 4);
  int* rpI = (int*)alloc((size_t)batch * (NI + 1) * 4);
  int* curU = (int*)alloc((size_t)batch * NU * 4);
  int* curI = (int*)alloc((size_t)batch * NI * 4);
  float* colsums = (float*)alloc(8 * DD * 4);  // [0..3]=user, [4..7]=item
  float* invs = (float*)alloc(8 * DD * 4);

  for (int b0 = 0; b0 < 4; b0 += batch) {
    hipMemsetAsync(cntU, 0, (size_t)batch * NU * 4, stream);
    hipMemsetAsync(cntI, 0, (size_t)batch * NI * 4, stream);
    dim3 hgrid(512, batch);
    hist_k<<<hgrid, 256, 0, stream>>>(ba, b0, cntU, cntI, NNZ_E);
    scan_k<<<2 * batch, 1024, 0, stream>>>(cntU, cntI, rpU, rpI, curU, curI, batch);
    scatter_k<<<hgrid, 256, 0, stream>>>(ba, b0, curU, curI, pairsU, pairsI, NNZ_E);
    for (int j = 0; j < batch; j++) {
      int b = b0 + j;
      float* o2u = (b < 3) ? u_slot[b] : nullptr;
      float* o2i = (b < 3) ? i_slot[b] : nullptr;
      gather_k<<<10000, 256, 0, stream>>>(rpU + (size_t)j * (NU + 1), pairsU + (size_t)j * NNZ_E,
                                          ii[b], l2nU + (size_t)b * NU * DD, o2u, NU);
      gather_k<<<5000, 256, 0, stream>>>(rpI + (size_t)j * (NI + 1), pairsI + (size_t)j * NNZ_E,
                                         uu[b], l2nI + (size_t)b * NI * DD, o2i, NI);
    }
  }

  gemm_sig_k<<<NU / 64, 256, 0, stream>>>(l2nU, (size_t)NU * DD, u_w, user_out, NU);
  gemm_sig_k<<<NI / 64, 256, 0, stream>>>(l2nI, (size_t)NI * DD, i_w, item_out, NI);

  hipMemsetAsync(colsums, 0, 8 * DD * 4, stream);
  colsq_k<<<dim3(512, 4), 256, 0, stream>>>(l2nU, (size_t)NU * DD, NU, colsums);
  colsq_k<<<dim3(512, 4), 256, 0, stream>>>(l2nI, (size_t)NI * DD, NI, colsums + 4 * DD);
  inv_k<<<4, 256, 0, stream>>>(colsums, invs, 8 * DD);
  scale_k<<<dim3(1024, 4), 256, 0, stream>>>(l2nU, (size_t)NU * 32, invs);
  scale_k<<<dim3(1024, 4), 256, 0, stream>>>(l2nI, (size_t)NI * 32, invs + 4 * DD);
}